// Round 5
// baseline (692.266 us; speedup 1.0000x reference)
//
#include <hip/hip_runtime.h>
#include <hip/hip_bf16.h>
#include <float.h>

#define DECAY 0.99f
#define OMD   0.01f
#define EPSF  1e-6f

constexpr int Bb = 8, Ss = 8192, Dd = 256, Kk = 2048;
constexpr int Nn = Bb * Ss;                 // 65536 rows

// ---- output layout (floats) ----
constexpr long OUT_QUANT = 0;                         // 16777216 floats
constexpr long OUT_IND   = (long)Nn * Dd;             // 16777216
constexpr long OUT_NCS   = OUT_IND + Nn;              // 16842752
constexpr long OUT_NEA   = OUT_NCS + Kk;              // 16844800
constexpr long OUT_NE    = OUT_NEA + (long)Kk * Dd;   // 17369088

// ---- workspace layout (floats) ----
constexpr long WS_COUNTS = 0;                         // K
constexpr long WS_TOTAL  = 2048;                      // 1
constexpr long WS_EE     = 2112;                      // K
constexpr long WS_BIG    = 4160;                      // partials / embed_sum
constexpr int  PARTS     = 8;                         // strip split for segsum

typedef __attribute__((ext_vector_type(8))) short short8;
typedef __attribute__((ext_vector_type(4))) float floatx4;

// split-bf16 certainty window: rows whose approx top-2 gap <= WINDOW get an
// exact fp32 rescan in pass 2 (error |approx-exact| << WINDOW/2, ~60 sigma).
#define WINDOW 0.0625f

// ============================================================
// Kernel A: x -> x_hi(bf16), x_lo = bf16(x - x_hi)
// ============================================================
__global__ __launch_bounds__(256) void convert_x_kernel(
    const float* __restrict__ x, ushort* __restrict__ x_hi, ushort* __restrict__ x_lo)
{
    long base = ((long)blockIdx.x * 256 + threadIdx.x) * 4;
    float4 v = *(const float4*)&x[base];
    float vv[4] = {v.x, v.y, v.z, v.w};
    ushort hh[4], ll[4];
    #pragma unroll
    for (int i = 0; i < 4; ++i) {
        __hip_bfloat16 hb = __float2bfloat16(vv[i]);
        float r = vv[i] - __bfloat162float(hb);
        __hip_bfloat16 lb = __float2bfloat16(r);
        hh[i] = *(ushort*)&hb; ll[i] = *(ushort*)&lb;
    }
    ushort4 h; h.x = hh[0]; h.y = hh[1]; h.z = hh[2]; h.w = hh[3];
    ushort4 l; l.x = ll[0]; l.y = ll[1]; l.z = ll[2]; l.w = ll[3];
    *(ushort4*)&x_hi[base] = h;
    *(ushort4*)&x_lo[base] = l;
}

// ============================================================
// Kernel B: embed -> e_hi, e_lo and ee[k] = sum_d embed[k][d]^2
// ============================================================
__global__ __launch_bounds__(256) void convert_e_kernel(
    const float* __restrict__ embed, ushort* __restrict__ e_hi,
    ushort* __restrict__ e_lo, float* __restrict__ ee)
{
    int row  = blockIdx.x * 4 + (threadIdx.x >> 6);
    int lane = threadIdx.x & 63;
    long base = (long)row * Dd + lane * 4;
    float4 v = *(const float4*)&embed[base];
    float vv[4] = {v.x, v.y, v.z, v.w};
    ushort hh[4], ll[4];
    float s = 0.0f;
    #pragma unroll
    for (int i = 0; i < 4; ++i) {
        s += vv[i] * vv[i];
        __hip_bfloat16 hb = __float2bfloat16(vv[i]);
        float r = vv[i] - __bfloat162float(hb);
        __hip_bfloat16 lb = __float2bfloat16(r);
        hh[i] = *(ushort*)&hb; ll[i] = *(ushort*)&lb;
    }
    ushort4 h; h.x = hh[0]; h.y = hh[1]; h.z = hh[2]; h.w = hh[3];
    ushort4 l; l.x = ll[0]; l.y = ll[1]; l.z = ll[2]; l.w = ll[3];
    *(ushort4*)&e_hi[base] = h;
    *(ushort4*)&e_lo[base] = l;
    #pragma unroll
    for (int off = 32; off >= 1; off >>= 1)
        s += __shfl_xor(s, off, 64);
    if (lane == 0) ee[row] = s;
}

// ============================================================
// Kernel C (pass 1) v2: MFMA split-bf16 fused GEMM + top-2 argmin.
// Block 128 rows x 128 codes, 4 waves 2x2 (wave tile 64x64).
// Per 32-wide k-slice: stage x_hi,x_lo,e_hi,e_lo slices (4 x 10 KB LDS),
// then acc += xh*eh + xl*eh + xh*el  (48 MFMA / 16 frag reads — round-4
// post-mortem: frag-read:MFMA ratio was the LDS-pipe bottleneck).
// Slice pitch 40 ushort = 5 x 16B chunks: frag-read bank-group =
// (5*row+quad) mod 8 -> exact 2-way = free (m136). Next-slice global loads
// prefetched into regs under the MFMA phase.
// ============================================================
constexpr int SP = 40;   // slice pitch in ushorts (80 B = 5 chunks)

__global__ __launch_bounds__(256)
void pass1_kernel(
    const ushort* __restrict__ x_hi, const ushort* __restrict__ x_lo,
    const ushort* __restrict__ e_hi, const ushort* __restrict__ e_lo,
    const float* __restrict__ ee, float* __restrict__ ind_out,
    int* __restrict__ qbase)
{
    __shared__ ushort xsh[128 * SP];   // 10240 B each
    __shared__ ushort xsl[128 * SP];
    __shared__ ushort esh[128 * SP];
    __shared__ ushort esl[128 * SP];
    __shared__ float  redv[2][128];
    __shared__ float  red2[2][128];
    __shared__ int    redi[2][128];

    const int tid  = threadIdx.x;
    const int lane = tid & 63;
    const int quad = lane >> 4;
    const int l15  = lane & 15;
    const int w    = tid >> 6;
    const int wy   = w >> 1;
    const int wx   = w & 1;
    const long row0 = (long)blockIdx.x * 128;

    // staging assignment: chunk kc of rows rr and rr+64 (64B/row segments,
    // coalesced 4-lane groups; LDS write chunk = 5*rr+kc -> ~3-way, writes
    // are only 20% of LDS traffic)
    const int kc   = tid & 3;
    const int rr   = tid >> 2;
    const int lds0 = rr * SP + kc * 8;
    const int lds1 = (rr + 64) * SP + kc * 8;

    float bestv[16], best2v[16];
    int   besti[16];
    #pragma unroll
    for (int i = 0; i < 16; ++i) { bestv[i] = FLT_MAX; best2v[i] = FLT_MAX; besti[i] = 0; }

    float4 pxh0, pxh1, pxl0, pxl1, peh0, peh1, pel0, pel1;

    // preload slice s (s = ct*8 + ks, 128 steps total)
    auto preload = [&](int s) {
        int ctn = (s >> 3) & 15;
        int ksn = s & 7;
        long xo0 = (row0 + rr) * Dd + ksn * 32 + kc * 8;
        long xo1 = xo0 + 64 * Dd;
        long eo0 = ((long)ctn * 128 + rr) * Dd + ksn * 32 + kc * 8;
        long eo1 = eo0 + 64 * Dd;
        pxh0 = *(const float4*)&x_hi[xo0];
        pxh1 = *(const float4*)&x_hi[xo1];
        pxl0 = *(const float4*)&x_lo[xo0];
        pxl1 = *(const float4*)&x_lo[xo1];
        peh0 = *(const float4*)&e_hi[eo0];
        peh1 = *(const float4*)&e_hi[eo1];
        pel0 = *(const float4*)&e_lo[eo0];
        pel1 = *(const float4*)&e_lo[eo1];
    };

    preload(0);
    int step = 0;

    for (int ct = 0; ct < 16; ++ct) {
        floatx4 acc[4][4];
        #pragma unroll
        for (int rt = 0; rt < 4; ++rt)
            #pragma unroll
            for (int jt = 0; jt < 4; ++jt)
                acc[rt][jt] = (floatx4){0.f, 0.f, 0.f, 0.f};

        for (int ks = 0; ks < 8; ++ks, ++step) {
            __syncthreads();                 // previous step's readers done
            *(float4*)&xsh[lds0] = pxh0;
            *(float4*)&xsh[lds1] = pxh1;
            *(float4*)&xsl[lds0] = pxl0;
            *(float4*)&xsl[lds1] = pxl1;
            *(float4*)&esh[lds0] = peh0;
            *(float4*)&esh[lds1] = peh1;
            *(float4*)&esl[lds0] = pel0;
            *(float4*)&esl[lds1] = pel1;
            __syncthreads();                 // writes visible

            preload(step + 1);               // hide global latency under MFMA

            short8 bh[4], ah[4], al[4], bl[4];
            #pragma unroll
            for (int jt = 0; jt < 4; ++jt)
                bh[jt] = *(const short8*)&esh[(wx * 64 + jt * 16 + l15) * SP + quad * 8];
            #pragma unroll
            for (int rt = 0; rt < 4; ++rt)
                ah[rt] = *(const short8*)&xsh[(wy * 64 + rt * 16 + l15) * SP + quad * 8];
            #pragma unroll
            for (int rt = 0; rt < 4; ++rt)
                #pragma unroll
                for (int jt = 0; jt < 4; ++jt)
                    acc[rt][jt] = __builtin_amdgcn_mfma_f32_16x16x32_bf16(
                        ah[rt], bh[jt], acc[rt][jt], 0, 0, 0);
            #pragma unroll
            for (int rt = 0; rt < 4; ++rt)
                al[rt] = *(const short8*)&xsl[(wy * 64 + rt * 16 + l15) * SP + quad * 8];
            #pragma unroll
            for (int rt = 0; rt < 4; ++rt)
                #pragma unroll
                for (int jt = 0; jt < 4; ++jt)
                    acc[rt][jt] = __builtin_amdgcn_mfma_f32_16x16x32_bf16(
                        al[rt], bh[jt], acc[rt][jt], 0, 0, 0);
            #pragma unroll
            for (int jt = 0; jt < 4; ++jt)
                bl[jt] = *(const short8*)&esl[(wx * 64 + jt * 16 + l15) * SP + quad * 8];
            #pragma unroll
            for (int rt = 0; rt < 4; ++rt)
                #pragma unroll
                for (int jt = 0; jt < 4; ++jt)
                    acc[rt][jt] = __builtin_amdgcn_mfma_f32_16x16x32_bf16(
                        ah[rt], bl[jt], acc[rt][jt], 0, 0, 0);
        }

        // fold tile into running top-2 per row
        #pragma unroll
        for (int jt = 0; jt < 4; ++jt) {
            int c = ct * 128 + wx * 64 + jt * 16 + l15;
            float eec = ee[c];
            #pragma unroll
            for (int rt = 0; rt < 4; ++rt) {
                #pragma unroll
                for (int reg = 0; reg < 4; ++reg) {
                    float s = eec - 2.0f * acc[rt][jt][reg];
                    int slot = rt * 4 + reg;
                    if (s < bestv[slot]) {
                        best2v[slot] = bestv[slot];
                        bestv[slot] = s; besti[slot] = c;
                    } else {
                        best2v[slot] = fminf(best2v[slot], s);
                    }
                }
            }
        }
    }

    // reduce top-2 across the 16 lanes of each quad (butterfly, width 16)
    #pragma unroll
    for (int slot = 0; slot < 16; ++slot) {
        float bv = bestv[slot]; int bi = besti[slot]; float b2 = best2v[slot];
        #pragma unroll
        for (int off = 8; off >= 1; off >>= 1) {
            float ov  = __shfl_xor(bv, off, 16);
            int   oi  = __shfl_xor(bi, off, 16);
            float ov2 = __shfl_xor(b2, off, 16);
            float nm2 = fminf(fminf(b2, ov2), fmaxf(bv, ov));
            if (ov < bv) { bv = ov; bi = oi; }
            b2 = nm2;
        }
        bestv[slot] = bv; besti[slot] = bi; best2v[slot] = b2;
    }

    // cross-wave (wx halves) combine via LDS
    if (l15 == 0) {
        #pragma unroll
        for (int rt = 0; rt < 4; ++rt)
            #pragma unroll
            for (int reg = 0; reg < 4; ++reg) {
                int rloc = wy * 64 + rt * 16 + quad * 4 + reg;
                int slot = rt * 4 + reg;
                redv[wx][rloc] = bestv[slot];
                red2[wx][rloc] = best2v[slot];
                redi[wx][rloc] = besti[slot];
            }
    }
    __syncthreads();
    if (tid < 128) {
        float v0 = redv[0][tid], v1 = redv[1][tid];
        float s0 = red2[0][tid], s1 = red2[1][tid];
        float m1, m2; int mi;
        if (v0 <= v1) { m1 = v0; mi = redi[0][tid]; m2 = fminf(fminf(s0, s1), v1); }
        else          { m1 = v1; mi = redi[1][tid]; m2 = fminf(fminf(s0, s1), v0); }
        long rowAbs = row0 + tid;
        ind_out[rowAbs] = (float)mi;
        if (m2 - m1 <= WINDOW) {
            int q = atomicAdd(qbase, 1);
            qbase[1 + q] = (int)rowAbs;
        }
    }
}

// ============================================================
// Kernel D (pass 2): exact fp32 rescan of ambiguous rows.
// ============================================================
__global__ __launch_bounds__(256) void pass2_kernel(
    const float* __restrict__ x, const float* __restrict__ embed,
    const float* __restrict__ ee, const int* __restrict__ qbase,
    float* __restrict__ ind_out)
{
    __shared__ float xs[256];
    __shared__ float sv[256];
    __shared__ int   si[256];
    const int tid = threadIdx.x;
    const int count = qbase[0];

    for (int qi = blockIdx.x; qi < count; qi += gridDim.x) {
        int row = qbase[1 + qi];
        __syncthreads();
        xs[tid] = x[(long)row * Dd + tid];
        __syncthreads();
        float bv = FLT_MAX; int bi = 0;
        for (int c = tid; c < Kk; c += 256) {
            const float* er = &embed[(long)c * Dd];
            float dot = 0.0f;
            for (int d = 0; d < Dd; ++d) dot += xs[d] * er[d];
            float s = ee[c] - 2.0f * dot;
            if (s < bv) { bv = s; bi = c; }
        }
        sv[tid] = bv; si[tid] = bi;
        __syncthreads();
        for (int off = 128; off >= 1; off >>= 1) {
            if (tid < off) {
                float v2 = sv[tid + off]; int i2 = si[tid + off];
                if (v2 < sv[tid] || (v2 == sv[tid] && i2 < si[tid])) {
                    sv[tid] = v2; si[tid] = i2;
                }
            }
            __syncthreads();
        }
        if (tid == 0) ind_out[row] = (float)si[0];
    }
}

// ============================================================
// Kernel E: quantize gather (pure BW, no atomics). One wave per row.
// ============================================================
__global__ __launch_bounds__(256) void quant_gather_kernel(
    const float* __restrict__ embed, const float* __restrict__ ind_f,
    float* __restrict__ quant)
{
    long row  = (long)blockIdx.x * 4 + (threadIdx.x >> 6);
    int  lane = threadIdx.x & 63;
    int  idx  = (int)ind_f[row];
    float4 ev = *(const float4*)&embed[(long)idx * Dd + lane * 4];
    *(float4*)&quant[row * Dd + lane * 4] = ev;
}

// ============================================================
// Kernel F: pull-based segmented sum (no hot-line atomics).
// ============================================================
template <int USE_ATOMIC>
__global__ __launch_bounds__(256) void segsum_kernel(
    const float* __restrict__ x, const float* __restrict__ ind_f,
    float* __restrict__ dst, float* __restrict__ counts)
{
    __shared__ float part[4][256];
    __shared__ float cnt_l[4];
    const int tid  = threadIdx.x;
    const int w    = tid >> 6;
    const int lane = tid & 63;
    const int k    = blockIdx.x >> 3;          // PARTS=8
    const int s    = blockIdx.x & 7;

    constexpr int STRIP = Nn / PARTS;          // 8192 rows
    constexpr int WAVE_ROWS = STRIP / 4;       // 2048 rows per wave
    const int base0 = s * STRIP + w * WAVE_ROWS;

    float4 acc = {0.f, 0.f, 0.f, 0.f};
    int cnt = 0;
    for (int win = 0; win < WAVE_ROWS; win += 64) {
        int idx = (int)ind_f[base0 + win + lane];
        unsigned long long m = __ballot(idx == k);
        cnt += __popcll(m);
        while (m) {
            int l = __ffsll((unsigned long long)m) - 1;
            m &= m - 1;
            long row = base0 + win + l;
            float4 v = *(const float4*)&x[row * Dd + lane * 4];
            acc.x += v.x; acc.y += v.y; acc.z += v.z; acc.w += v.w;
        }
    }
    *(float4*)&part[w][lane * 4] = acc;
    if (lane == 0) cnt_l[w] = (float)cnt;
    __syncthreads();
    float sum = part[0][tid] + part[1][tid] + part[2][tid] + part[3][tid];
    if (USE_ATOMIC) {
        if (sum != 0.0f) atomicAdd(&dst[(long)k * Dd + tid], sum);
    } else {
        dst[((long)s * Kk + k) * Dd + tid] = sum;
    }
    if (tid == 0)
        atomicAdd(&counts[k], cnt_l[0] + cnt_l[1] + cnt_l[2] + cnt_l[3]);
}

// ============================================================
// Kernel G: new_cluster_size + total (single block)
// ============================================================
__global__ __launch_bounds__(256) void ema_cs_kernel(
    const float* __restrict__ cs, const float* __restrict__ counts,
    float* __restrict__ ncs, float* __restrict__ total_ws)
{
    __shared__ float red[256];
    int tid = threadIdx.x;
    float s = 0.0f;
    #pragma unroll
    for (int i = 0; i < 8; ++i) {
        int k = tid + i * 256;
        float v = cs[k] * DECAY + OMD * counts[k];
        ncs[k] = v;
        s += v;
    }
    red[tid] = s;
    __syncthreads();
    #pragma unroll
    for (int off = 128; off >= 1; off >>= 1) {
        if (tid < off) red[tid] += red[tid + off];
        __syncthreads();
    }
    if (tid == 0) total_ws[0] = red[0];
}

// ============================================================
// Kernel H: combine partials -> embed_sum; nea; ne.
// ============================================================
__global__ __launch_bounds__(256) void nea_ne_kernel(
    const float* __restrict__ ea, const float* __restrict__ partials,
    int nparts, const float* __restrict__ ncs, const float* __restrict__ total_ws,
    float* __restrict__ nea, float* __restrict__ ne)
{
    long g = ((long)blockIdx.x * 256 + threadIdx.x) * 4;
    int  k = (int)(g >> 8);
    int  d = (int)(g & 255);

    float4 sv = {0.f, 0.f, 0.f, 0.f};
    for (int p = 0; p < nparts; ++p) {
        float4 pv = *(const float4*)&partials[((long)p * Kk + k) * Dd + d];
        sv.x += pv.x; sv.y += pv.y; sv.z += pv.z; sv.w += pv.w;
    }

    float4 av = *(const float4*)&ea[g];
    float4 out_nea;
    out_nea.x = av.x * DECAY + OMD * sv.x;
    out_nea.y = av.y * DECAY + OMD * sv.y;
    out_nea.z = av.z * DECAY + OMD * sv.z;
    out_nea.w = av.w * DECAY + OMD * sv.w;
    *(float4*)&nea[g] = out_nea;

    float total = total_ws[0];
    float sm = (ncs[k] + EPSF) / (total + EPSF * (float)Kk) * total;
    float inv = 1.0f / sm;
    float4 out_ne;
    out_ne.x = out_nea.x * inv;
    out_ne.y = out_nea.y * inv;
    out_ne.z = out_nea.z * inv;
    out_ne.w = out_nea.w * inv;
    *(float4*)&ne[g] = out_ne;
}

// ============================================================
extern "C" void kernel_launch(void* const* d_in, const int* in_sizes, int n_in,
                              void* d_out, int out_size, void* d_ws, size_t ws_size,
                              hipStream_t stream)
{
    const float* x     = (const float*)d_in[0];
    const float* embed = (const float*)d_in[1];
    const float* cs    = (const float*)d_in[2];
    const float* ea    = (const float*)d_in[3];

    float* out   = (float*)d_out;
    float* quant = out + OUT_QUANT;
    float* ind_f = out + OUT_IND;
    float* ncs   = out + OUT_NCS;
    float* nea   = out + OUT_NEA;
    float* ne    = out + OUT_NE;

    float* ws     = (float*)d_ws;
    float* counts = ws + WS_COUNTS;
    float* total  = ws + WS_TOTAL;
    float* ee     = ws + WS_EE;
    float* big    = ws + WS_BIG;

    // scratch inside d_out (regions overwritten later by final writers)
    ushort* x_hi = (ushort*)(out + OUT_QUANT);
    ushort* x_lo = (ushort*)(out + OUT_QUANT + Nn * (Dd / 2));
    ushort* e_hi = (ushort*)(out + OUT_NEA);
    ushort* e_lo = (ushort*)(out + OUT_NEA + Kk * (Dd / 2));
    int*    qb   = (int*)(out + OUT_NE);

    const size_t need_partials =
        (size_t)(WS_BIG + (long)PARTS * Kk * Dd) * sizeof(float) + 1024;
    const bool use_ws_partials = ws_size >= need_partials;

    hipMemsetAsync(counts, 0, Kk * sizeof(float), stream);
    hipMemsetAsync(qb, 0, sizeof(int), stream);
    if (!use_ws_partials)
        hipMemsetAsync(big, 0, (size_t)Kk * Dd * sizeof(float), stream);

    convert_x_kernel<<<(Nn * Dd / 4) / 256, 256, 0, stream>>>(x, x_hi, x_lo);
    convert_e_kernel<<<Kk / 4, 256, 0, stream>>>(embed, e_hi, e_lo, ee);
    pass1_kernel<<<Nn / 128, 256, 0, stream>>>(x_hi, x_lo, e_hi, e_lo, ee, ind_f, qb);
    pass2_kernel<<<256, 256, 0, stream>>>(x, embed, ee, qb, ind_f);
    quant_gather_kernel<<<Nn / 4, 256, 0, stream>>>(embed, ind_f, quant);
    if (use_ws_partials)
        segsum_kernel<0><<<Kk * PARTS, 256, 0, stream>>>(x, ind_f, big, counts);
    else
        segsum_kernel<1><<<Kk * PARTS, 256, 0, stream>>>(x, ind_f, big, counts);
    ema_cs_kernel<<<1, 256, 0, stream>>>(cs, counts, ncs, total);
    nea_ne_kernel<<<(Kk * Dd / 4) / 256, 256, 0, stream>>>(
        ea, big, use_ws_partials ? PARTS : 1, ncs, total, nea, ne);
}